// Round 6
// baseline (170.095 us; speedup 1.0000x reference)
//
#include <hip/hip_runtime.h>
#include <math.h>

// ---------------- problem constants ----------------
#define B_TOT 8192
#define KE 400      // 16 nodes * 25 t (ecc K)
#define KR 300      // 12 nodes * 25 t (err K)
#define MEP 416     // ecc K padded to 13*32
#define MRP 320     // err K padded to 10*32
#define ROWS 16     // batch rows per fused block

// LDS strides (bf16 elements), padded for bank-conflict avoidance
#define SXE_LD 424
#define SXR_LD 328
#define SEH_LD 72

// ---------------- workspace layout ----------------
// float offsets: bias partials (no atomics, no zero-init needed)
#define OFF_BE 0        // bias_ecc partials [4][256]
#define OFF_BR 1024     // bias_err partials [3][256]
// ushort offsets (from d_ws base viewed as ushort*), 16B-aligned
#define U_AET 14080                   // AwT_ecc [256][416] bf16
#define U_ART (U_AET + 256 * MEP)     // AwT_err [256][320] bf16
#define U_WET (U_ART + 256 * MRP)     // WeT     [64][64]  bf16

typedef __attribute__((ext_vector_type(8))) short short8;
typedef __attribute__((ext_vector_type(4))) float floatx4;

__device__ __forceinline__ float sigmoidf_(float x) { return 1.f / (1.f + __expf(-x)); }
__device__ __forceinline__ float tanhf_(float x) { float e = __expf(2.f * x); return (e - 1.f) / (e + 1.f); }
__device__ __forceinline__ unsigned short f2bf(float x) {
    unsigned u = __float_as_uint(x);
    u += 0x7fffu + ((u >> 16) & 1u);          // round-to-nearest-even
    return (unsigned short)(u >> 16);
}

// =====================================================================
// Kernel 1 (merged fold): every block is self-contained (no inter-kernel
// or inter-block dependency).
//   blk < 736          : one AwT row k (Weff recomputed locally in LDS)
//   blk in [736, 743)  : bias partials (cvec recomputed locally in LDS)
//   blk == 743         : WeT transpose
// grid = 744 blocks x 256 threads
// =====================================================================
__global__ __launch_bounds__(256) void fold_all(
    const float* __restrict__ wt_ecc, const float* __restrict__ bt_ecc,
    const float* __restrict__ wt_err, const float* __restrict__ bt_err,
    const float* __restrict__ W0_ecc, const float* __restrict__ W1_ecc, const float* __restrict__ b_ecc,
    const float* __restrict__ W0_err, const float* __restrict__ W1_err, const float* __restrict__ b_err,
    const float* __restrict__ Wp_ecc, const float* __restrict__ bp_ecc,
    const float* __restrict__ Wp_err, const float* __restrict__ bp_err,
    const float* __restrict__ We,
    float* __restrict__ wsf, unsigned short* __restrict__ wsu)
{
    const int blk = blockIdx.x;
    const int tid = threadIdx.x;
    __shared__ float red[4][64];
    __shared__ float comb[2][64];

    if (blk < MEP + MRP) {
        const bool is_err = blk >= MEP;
        const int k  = is_err ? blk - MEP : blk;
        const int K  = is_err ? KR : KE;
        const int MP = is_err ? MRP : MEP;
        unsigned short* dst = wsu + (is_err ? U_ART : U_AET);
        if (k >= K) { dst[(size_t)tid * MP + k] = 0; return; }   // zero pad rows

        const int v = k / 25, tin = k % 25;
        const int V = is_err ? 12 : 16;
        const int vp = (v + 1) % V, vm = (v + V - 1) % V;
        const float* wt = is_err ? wt_err : wt_ecc;
        const float* W0 = is_err ? W0_err : W0_ecc;
        const float* W1 = is_err ? W1_err : W1_ecc;
        const float* Wp = is_err ? Wp_err : Wp_ecc;

        // cooperative Weff: part = (order<<1)|chalf, g = lane
        const int part = tid >> 6, g = tid & 63;
        const float* W = (part >> 1) ? W1 : W0;
        const int c0 = (part & 1) * 16;
        const int t0 = tin > 0 ? tin - 1 : 0;
        const int t1 = tin < 24 ? tin + 1 : 24;
        float s = 0.f;
        for (int ci = 0; ci < 16; ++ci) {
            const int c = c0 + ci;
            for (int t = t0; t <= t1; ++t)
                s = fmaf(wt[c * 3 + (tin - t + 1)], W[(c * 25 + t) * 64 + g], s);
        }
        red[part][g] = s;
        __syncthreads();
        if (tid < 128) {
            const int o = tid >> 6;                        // 0: w0, 1: w1
            comb[o][g] = red[o * 2 + 0][g] + red[o * 2 + 1][g];
        }
        __syncthreads();

        const int h = tid;
        float acc = 0.f;
        #pragma unroll 4
        for (int g2 = 0; g2 < 64; ++g2) {
            acc = fmaf(comb[0][g2], Wp[(v * 64 + g2) * 256 + h], acc);
            acc = fmaf(-0.5f * comb[1][g2], Wp[(vp * 64 + g2) * 256 + h] + Wp[(vm * 64 + g2) * 256 + h], acc);
        }
        dst[(size_t)h * MP + k] = f2bf(acc);
    } else if (blk < MEP + MRP + 7) {
        const int bi = blk - (MEP + MRP);     // 0..6: 0-3 ecc partials, 4-6 err partials
        const bool is_err = bi >= 4;
        const int i = is_err ? bi - 4 : bi;
        const float* bt = is_err ? bt_err : bt_ecc;
        const float* W0 = is_err ? W0_err : W0_ecc;
        const float* W1 = is_err ? W1_err : W1_ecc;
        const float* bb = is_err ? b_err : b_ecc;
        const float* Wp = is_err ? Wp_err : Wp_ecc;
        const float* bp = is_err ? bp_err : bp_ecc;

        // cvec cooperative: g = lane, cq = quarter handles 8 channels
        const int g = tid & 63, cq = tid >> 6;
        float s = 0.f;
        for (int c8 = 0; c8 < 8; ++c8) {
            const int c = cq * 8 + c8;
            const float btc = bt[c];
            #pragma unroll
            for (int t = 0; t < 25; ++t) {
                const int ct = (c * 25 + t) * 64 + g;
                s = fmaf(btc, W0[ct] - W1[ct], s);
            }
        }
        red[cq][g] = s;
        __syncthreads();
        if (tid < 64)
            comb[0][g] = bb[g] + red[0][g] + red[1][g] + red[2][g] + red[3][g];
        __syncthreads();

        // partial bias over j in [i*256, (i+1)*256)
        const int h = tid;
        float acc = (i == 0) ? bp[h] : 0.f;
        #pragma unroll 4
        for (int jj = 0; jj < 256; ++jj) {
            const int j = i * 256 + jj;
            acc = fmaf(comb[0][j & 63], Wp[(size_t)j * 256 + h], acc);
        }
        wsf[(is_err ? OFF_BR : OFF_BE) + i * 256 + h] = acc;
    } else {
        // WeT[e][d] = We[d][e], bf16
        for (int it = 0; it < 16; ++it) {
            const int idx = it * 256 + tid;
            const int e = idx >> 6, d = idx & 63;
            wsu[U_WET + e * 64 + d] = f2bf(We[d * 64 + e]);
        }
    }
}

// =====================================================================
// Kernel 2 (fused): per-block 16 batch rows, 4 waves (one 64-col slab each).
// grid = 512 blocks; LDS 26.4 KB. Epilogue in registers + shfl;
// bias read as partial sums (4 ecc + 3 err slots).
// =====================================================================
__global__ __launch_bounds__(256, 4) void fused_main(
    const float* __restrict__ ecc, const float* __restrict__ err, const float* __restrict__ ehr,
    const float* __restrict__ wsf, const unsigned short* __restrict__ wsu,
    const float* __restrict__ Wa, const float* __restrict__ ba,
    const float* __restrict__ be_, const float* __restrict__ Wf2, const float* __restrict__ bf2,
    float* __restrict__ out)
{
    const unsigned short* awt_e = wsu + U_AET;
    const unsigned short* awt_r = wsu + U_ART;
    const unsigned short* wet   = wsu + U_WET;
    const float* biasE = wsf + OFF_BE;   // [4][256] partials
    const float* biasR = wsf + OFF_BR;   // [3][256] partials

    __shared__ __align__(16) char smem[ROWS * (SXE_LD + SXR_LD + SEH_LD) * 2];
    unsigned short* sxe = (unsigned short*)smem;          // [16][SXE_LD]
    unsigned short* sxr = sxe + ROWS * SXE_LD;            // [16][SXR_LD]
    unsigned short* seh = sxr + ROWS * SXR_LD;            // [16][SEH_LD]
    // epilogue scratch overlays sxe (used only after the post-MFMA barrier)
    float* pa_part = (float*)smem;                        // [4][16]
    float* at_arr  = pa_part + 64;                        // [16]
    float* po_part = at_arr + 16;                         // [4][16]

    const int tid = threadIdx.x;
    const int row0 = blockIdx.x * ROWS;

    // ---- stage X_ecc: 16 rows x 106 quads (real quads < 100) ----
    for (int it = 0; it < 7; ++it) {
        const int f = it * 256 + tid;
        if (f < ROWS * 106) {
            const int r = f / 106, q = f - r * 106;
            float4 v = make_float4(0.f, 0.f, 0.f, 0.f);
            if (q < 100) v = *(const float4*)(ecc + (size_t)(row0 + r) * KE + q * 4);
            const unsigned p0 = (unsigned)f2bf(v.x) | ((unsigned)f2bf(v.y) << 16);
            const unsigned p1 = (unsigned)f2bf(v.z) | ((unsigned)f2bf(v.w) << 16);
            *(uint2*)&sxe[r * SXE_LD + q * 4] = make_uint2(p0, p1);
        }
    }
    // ---- stage X_err: 16 rows x 82 quads (real quads < 75) ----
    for (int it = 0; it < 6; ++it) {
        const int f = it * 256 + tid;
        if (f < ROWS * 82) {
            const int r = f / 82, q = f - r * 82;
            float4 v = make_float4(0.f, 0.f, 0.f, 0.f);
            if (q < 75) v = *(const float4*)(err + (size_t)(row0 + r) * KR + q * 4);
            const unsigned p0 = (unsigned)f2bf(v.x) | ((unsigned)f2bf(v.y) << 16);
            const unsigned p1 = (unsigned)f2bf(v.z) | ((unsigned)f2bf(v.w) << 16);
            *(uint2*)&sxr[r * SXR_LD + q * 4] = make_uint2(p0, p1);
        }
    }
    // ---- stage ehr: 16 rows x 16 quads exactly (256 entries) ----
    {
        const int r = tid >> 4, q = tid & 15;
        const float4 v = *(const float4*)(ehr + (size_t)(row0 + r) * 64 + q * 4);
        const unsigned p0 = (unsigned)f2bf(v.x) | ((unsigned)f2bf(v.y) << 16);
        const unsigned p1 = (unsigned)f2bf(v.z) | ((unsigned)f2bf(v.w) << 16);
        *(uint2*)&seh[r * SEH_LD + q * 4] = make_uint2(p0, p1);
    }
    __syncthreads();

    const int wv = tid >> 6, lane = tid & 63;
    const int lm = lane & 15, lq = lane >> 4;
    const int n0 = wv * 64;

    floatx4 accE[4], accR[4], accH;
    accH = (floatx4){0.f, 0.f, 0.f, 0.f};
    #pragma unroll
    for (int nt = 0; nt < 4; ++nt) {
        accE[nt] = (floatx4){0.f, 0.f, 0.f, 0.f};
        accR[nt] = (floatx4){0.f, 0.f, 0.f, 0.f};
    }

    // ---- ehr_p = ehr @ We : wave handles e-slab wv (e = 16*wv + lm) ----
    #pragma unroll
    for (int kc = 0; kc < 2; ++kc) {
        const short8 b = *(const short8*)(wet + (wv * 16 + lm) * 64 + kc * 32 + lq * 8);
        const short8 a = *(const short8*)&seh[lm * SEH_LD + kc * 32 + lq * 8];
        accH = __builtin_amdgcn_mfma_f32_16x16x32_bf16(a, b, accH, 0, 0, 0);
    }
    // ---- ecc branch: 13 k-chunks ----
    #pragma unroll
    for (int kc = 0; kc < 13; ++kc) {
        const short8 a0 = *(const short8*)&sxe[lm * SXE_LD + kc * 32 + lq * 8];
        #pragma unroll
        for (int nt = 0; nt < 4; ++nt) {
            const short8 b = *(const short8*)(awt_e + (size_t)(n0 + nt * 16 + lm) * MEP + kc * 32 + lq * 8);
            accE[nt] = __builtin_amdgcn_mfma_f32_16x16x32_bf16(a0, b, accE[nt], 0, 0, 0);
        }
    }
    // ---- err branch: 10 k-chunks ----
    #pragma unroll
    for (int kc = 0; kc < 10; ++kc) {
        const short8 a0 = *(const short8*)&sxr[lm * SXR_LD + kc * 32 + lq * 8];
        #pragma unroll
        for (int nt = 0; nt < 4; ++nt) {
            const short8 b = *(const short8*)(awt_r + (size_t)(n0 + nt * 16 + lm) * MRP + kc * 32 + lq * 8);
            accR[nt] = __builtin_amdgcn_mfma_f32_16x16x32_bf16(a0, b, accR[nt], 0, 0, 0);
        }
    }

    // ---- per-lane epilogue constants (L2-hot; bias = sum of partials) ----
    float bE[4], bR[4], wa[4], wf[4];
    #pragma unroll
    for (int nt = 0; nt < 4; ++nt) {
        const int h = n0 + nt * 16 + lm;
        bE[nt] = biasE[h] + biasE[256 + h] + biasE[512 + h] + biasE[768 + h];
        bR[nt] = biasR[h] + biasR[256 + h] + biasR[512 + h];
        wa[nt] = Wa[h]; wf[nt] = Wf2[h];
    }
    const int e_lane = wv * 16 + lm;
    const float eh_be = be_[e_lane];
    const float eh_wf = Wf2[256 + e_lane];

    // ---- pass 1: attention logits, pure register + shfl ----
    float pa_lane[4];
    #pragma unroll
    for (int rg = 0; rg < 4; ++rg) {
        float s = 0.f;
        #pragma unroll
        for (int nt = 0; nt < 4; ++nt) {
            const float ev = accE[nt][rg] + bE[nt];
            const float rv = accR[nt][rg] + bR[nt];
            s = fmaf(tanhf_(ev + rv), wa[nt], s);
        }
        s += __shfl_xor(s, 1, 64); s += __shfl_xor(s, 2, 64);
        s += __shfl_xor(s, 4, 64); s += __shfl_xor(s, 8, 64);
        pa_lane[rg] = s;
    }

    __syncthreads();   // all staging-LDS reads complete; safe to overlay scratch
    if (lm == 0) {
        #pragma unroll
        for (int rg = 0; rg < 4; ++rg)
            pa_part[wv * 16 + lq * 4 + rg] = pa_lane[rg];
    }
    __syncthreads();
    if (tid < 16)
        at_arr[tid] = sigmoidf_(pa_part[tid] + pa_part[16 + tid] + pa_part[32 + tid] + pa_part[48 + tid] + ba[0]);
    __syncthreads();

    // ---- pass 2: fused + EHR dot with Wf2, register + shfl ----
    float po_lane[4];
    #pragma unroll
    for (int rg = 0; rg < 4; ++rg) {
        const int r = lq * 4 + rg;
        const float at = at_arr[r];
        const float om = 1.f - at;
        float s = 0.f;
        #pragma unroll
        for (int nt = 0; nt < 4; ++nt) {
            const float ev = accE[nt][rg] + bE[nt];
            const float rv = accR[nt][rg] + bR[nt];
            s = fmaf(fmaxf(at * ev + om * rv, 0.f), wf[nt], s);
        }
        s = fmaf(fmaxf(accH[rg] + eh_be, 0.f), eh_wf, s);
        s += __shfl_xor(s, 1, 64); s += __shfl_xor(s, 2, 64);
        s += __shfl_xor(s, 4, 64); s += __shfl_xor(s, 8, 64);
        po_lane[rg] = s;
    }
    if (lm == 0) {
        #pragma unroll
        for (int rg = 0; rg < 4; ++rg)
            po_part[wv * 16 + lq * 4 + rg] = po_lane[rg];
    }
    __syncthreads();
    if (tid < 16)
        out[row0 + tid] = sigmoidf_(po_part[tid] + po_part[16 + tid] + po_part[32 + tid] + po_part[48 + tid] + bf2[0]);
}

// =====================================================================
extern "C" void kernel_launch(void* const* d_in, const int* in_sizes, int n_in,
                              void* d_out, int out_size, void* d_ws, size_t ws_size,
                              hipStream_t stream)
{
    (void)in_sizes; (void)n_in; (void)out_size; (void)ws_size;
    const float* ecc    = (const float*)d_in[0];
    const float* err    = (const float*)d_in[1];
    const float* ehr    = (const float*)d_in[2];
    const float* wt_ecc = (const float*)d_in[3];
    const float* bt_ecc = (const float*)d_in[4];
    const float* wt_err = (const float*)d_in[5];
    const float* bt_err = (const float*)d_in[6];
    const float* W0_ecc = (const float*)d_in[7];
    const float* W1_ecc = (const float*)d_in[8];
    const float* b_ecc  = (const float*)d_in[9];
    const float* W0_err = (const float*)d_in[10];
    const float* W1_err = (const float*)d_in[11];
    const float* b_err  = (const float*)d_in[12];
    const float* Wp_ecc = (const float*)d_in[13];
    const float* bp_ecc = (const float*)d_in[14];
    const float* Wp_err = (const float*)d_in[15];
    const float* bp_err = (const float*)d_in[16];
    const float* Wa     = (const float*)d_in[17];
    const float* ba     = (const float*)d_in[18];
    const float* We     = (const float*)d_in[19];
    const float* be     = (const float*)d_in[20];
    const float* Wf2    = (const float*)d_in[21];
    const float* bf2    = (const float*)d_in[22];
    float* wsf = (float*)d_ws;
    unsigned short* wsu = (unsigned short*)d_ws;
    float* out = (float*)d_out;

    fold_all<<<dim3(MEP + MRP + 7 + 1), dim3(256), 0, stream>>>(
        wt_ecc, bt_ecc, wt_err, bt_err, W0_ecc, W1_ecc, b_ecc, W0_err, W1_err, b_err,
        Wp_ecc, bp_ecc, Wp_err, bp_err, We, wsf, wsu);
    fused_main<<<dim3(B_TOT / ROWS), dim3(256), 0, stream>>>(
        ecc, err, ehr, wsf, wsu, Wa, ba, be, Wf2, bf2, out);
}

// Round 7
// 159.077 us; speedup vs baseline: 1.0693x; 1.0693x over previous
//
#include <hip/hip_runtime.h>
#include <math.h>

// ---------------- problem constants ----------------
#define B_TOT 8192
#define KE 400      // 16 nodes * 25 t (ecc K)
#define KR 300      // 12 nodes * 25 t (err K)
#define MEP 416     // ecc K padded to 13*32
#define MRP 320     // err K padded to 10*32
#define ROWS 16     // batch rows per fused block

// LDS strides (bf16 elements), padded for bank-conflict avoidance
#define SXE_LD 424
#define SXR_LD 328
#define SEH_LD 72

// ---------------- workspace layout ----------------
// float offsets
#define OFF_WEFF0E 0
#define OFF_WEFF1E 1600
#define OFF_WEFF0R 3200
#define OFF_WEFF1R 4800
#define OFF_CVE    6400
#define OFF_CVR    6464
#define OFF_BE     6528     // bias_ecc partials [8][256]
#define OFF_BR     8576     // bias_err partials [6][256]
// ushort offsets (from d_ws base viewed as ushort*), 16B-aligned
#define U_AET 20480                   // AwT_ecc [256][416] bf16
#define U_ART (U_AET + 256 * MEP)     // AwT_err [256][320] bf16
#define U_WET (U_ART + 256 * MRP)     // WeT     [64][64]  bf16

typedef __attribute__((ext_vector_type(8))) short short8;
typedef __attribute__((ext_vector_type(4))) float floatx4;

__device__ __forceinline__ float sigmoidf_(float x) { return 1.f / (1.f + __expf(-x)); }
__device__ __forceinline__ float tanhf_(float x) { float e = __expf(2.f * x); return (e - 1.f) / (e + 1.f); }
__device__ __forceinline__ unsigned short f2bf(float x) {
    unsigned u = __float_as_uint(x);
    u += 0x7fffu + ((u >> 16) & 1u);          // round-to-nearest-even
    return (unsigned short)(u >> 16);
}

// =====================================================================
// Kernel 1: fold Conv1d into W0/W1 -> Weff [25][64] per (branch, order),
// cvec[64] = b + sum_ct bt[c]*(W0-W1)[ct]  (ring row-sum of L_hat = -1).
// grid = 102 blocks x 256 threads
// =====================================================================
__global__ __launch_bounds__(256) void fold_temporal(
    const float* __restrict__ wt_ecc, const float* __restrict__ bt_ecc,
    const float* __restrict__ wt_err, const float* __restrict__ bt_err,
    const float* __restrict__ W0_ecc, const float* __restrict__ W1_ecc, const float* __restrict__ b_ecc,
    const float* __restrict__ W0_err, const float* __restrict__ W1_err, const float* __restrict__ b_err,
    float* __restrict__ ws)
{
    const int blk = blockIdx.x;
    const int tid = threadIdx.x;
    const int cq = tid >> 6;    // 0..3  (c-chunk of 8)
    const int g  = tid & 63;

    __shared__ float red[4][64];

    if (blk < 100) {
        const int m = blk / 25;       // 0: W0_ecc, 1: W1_ecc, 2: W0_err, 3: W1_err
        const int tin = blk % 25;
        const bool is_err = (m >= 2);
        const float* wt = is_err ? wt_err : wt_ecc;
        const float* W = (m & 1) ? (is_err ? W1_err : W1_ecc) : (is_err ? W0_err : W0_ecc);
        const int t0 = tin > 0 ? tin - 1 : 0;
        const int t1 = tin < 24 ? tin + 1 : 24;
        float s = 0.f;
        #pragma unroll
        for (int c8 = 0; c8 < 8; ++c8) {
            const int c = cq * 8 + c8;
            for (int t = t0; t <= t1; ++t) {
                const int k = tin - t + 1;           // 0..2
                s = fmaf(wt[c * 3 + k], W[(c * 25 + t) * 64 + g], s);
            }
        }
        red[cq][g] = s;
        __syncthreads();
        if (tid < 64)
            ws[m * 1600 + tin * 64 + g] = red[0][g] + red[1][g] + red[2][g] + red[3][g];
    } else {
        const bool is_err = (blk == 101);
        const float* bt = is_err ? bt_err : bt_ecc;
        const float* W0 = is_err ? W0_err : W0_ecc;
        const float* W1 = is_err ? W1_err : W1_ecc;
        const float* bb = is_err ? b_err : b_ecc;
        float s = 0.f;
        #pragma unroll
        for (int c8 = 0; c8 < 8; ++c8) {
            const int c = cq * 8 + c8;
            const float btc = bt[c];
            #pragma unroll
            for (int t = 0; t < 25; ++t) {
                const int ct = (c * 25 + t) * 64 + g;
                s = fmaf(btc, W0[ct] - W1[ct], s);
            }
        }
        red[cq][g] = s;
        __syncthreads();
        if (tid < 64)
            ws[(is_err ? OFF_CVR : OFF_CVE) + g] =
                bb[g] + red[0][g] + red[1][g] + red[2][g] + red[3][g];
    }
}

// =====================================================================
// Kernel 2 (v2): AwT via per-(branch, v) blocks — each block computes all
// 25 tin-rows, amortizing the 192 Wp row-loads 25x. Weff staged transposed
// in LDS ([g][tin], float4-readable). Plus pad-row zeroing, bias partials
// (8 ecc + 6 err x 128 terms, no atomics), WeT transpose.
// grid = 28 + 1 + 14 + 1 = 44 blocks x 256 threads
// =====================================================================
__global__ __launch_bounds__(256) void fold_graph(
    const float* __restrict__ Wp_ecc, const float* __restrict__ bp_ecc,
    const float* __restrict__ Wp_err, const float* __restrict__ bp_err,
    const float* __restrict__ We,
    float* __restrict__ wsf, unsigned short* __restrict__ wsu)
{
    const int blk = blockIdx.x;
    const int tid = threadIdx.x;

    if (blk < 28) {
        const bool is_err = blk >= 16;
        const int v  = is_err ? blk - 16 : blk;
        const int V  = is_err ? 12 : 16;
        const int MP = is_err ? MRP : MEP;
        const float* Wp = is_err ? Wp_err : Wp_ecc;
        const float* wsrc0 = wsf + (is_err ? OFF_WEFF0R : OFF_WEFF0E);
        const float* wsrc1 = wsf + (is_err ? OFF_WEFF1R : OFF_WEFF1E);
        unsigned short* dst = wsu + (is_err ? U_ART : U_AET);
        const int vp = (v + 1) % V, vm = (v + V - 1) % V;

        __shared__ __align__(16) float w0T[64][28];
        __shared__ __align__(16) float w1T[64][28];
        for (int i = tid; i < 64 * 28; i += 256) {
            ((float*)w0T)[i] = 0.f; ((float*)w1T)[i] = 0.f;
        }
        __syncthreads();
        for (int i = tid; i < 1600; i += 256) {
            const int tin = i >> 6, g = i & 63;
            w0T[g][tin] = wsrc0[i];
            w1T[g][tin] = -0.5f * wsrc1[i];
        }
        __syncthreads();

        const int h = tid;
        float acc[25];
        #pragma unroll
        for (int t = 0; t < 25; ++t) acc[t] = 0.f;

        #pragma unroll 2
        for (int g = 0; g < 64; ++g) {
            const float p0 = Wp[(size_t)(v  * 64 + g) * 256 + h];
            const float ps = Wp[(size_t)(vm * 64 + g) * 256 + h]
                           + Wp[(size_t)(vp * 64 + g) * 256 + h];
            #pragma unroll
            for (int tc = 0; tc < 6; ++tc) {
                const float4 a = *(const float4*)&w0T[g][tc * 4];
                const float4 b = *(const float4*)&w1T[g][tc * 4];
                acc[tc * 4 + 0] = fmaf(a.x, p0, fmaf(b.x, ps, acc[tc * 4 + 0]));
                acc[tc * 4 + 1] = fmaf(a.y, p0, fmaf(b.y, ps, acc[tc * 4 + 1]));
                acc[tc * 4 + 2] = fmaf(a.z, p0, fmaf(b.z, ps, acc[tc * 4 + 2]));
                acc[tc * 4 + 3] = fmaf(a.w, p0, fmaf(b.w, ps, acc[tc * 4 + 3]));
            }
            acc[24] = fmaf(w0T[g][24], p0, fmaf(w1T[g][24], ps, acc[24]));
        }
        #pragma unroll
        for (int t = 0; t < 25; ++t)
            dst[(size_t)h * MP + v * 25 + t] = f2bf(acc[t]);
    } else if (blk == 28) {
        // zero pad rows: ecc k=400..415, err k=300..319 (for every h)
        for (int i = tid; i < 256 * 16; i += 256) {
            const int h = i >> 4, k = 400 + (i & 15);
            wsu[U_AET + (size_t)h * MEP + k] = 0;
        }
        for (int i = tid; i < 256 * 20; i += 256) {
            const int h = i / 20, k = 300 + (i % 20);
            wsu[U_ART + (size_t)h * MRP + k] = 0;
        }
    } else if (blk < 29 + 8) {
        // bias_ecc partial i: j in [i*128, (i+1)*128), 1024 terms total
        const int i = blk - 29;
        const float* cv = wsf + OFF_CVE;
        const int h = tid;
        float acc = (i == 0) ? bp_ecc[h] : 0.f;
        #pragma unroll 4
        for (int jj = 0; jj < 128; ++jj) {
            const int j = i * 128 + jj;
            acc = fmaf(cv[j & 63], Wp_ecc[(size_t)j * 256 + h], acc);
        }
        wsf[OFF_BE + i * 256 + h] = acc;
    } else if (blk < 37 + 6) {
        // bias_err partial i: j in [i*128, (i+1)*128), 768 terms total
        const int i = blk - 37;
        const float* cv = wsf + OFF_CVR;
        const int h = tid;
        float acc = (i == 0) ? bp_err[h] : 0.f;
        #pragma unroll 4
        for (int jj = 0; jj < 128; ++jj) {
            const int j = i * 128 + jj;
            acc = fmaf(cv[j & 63], Wp_err[(size_t)j * 256 + h], acc);
        }
        wsf[OFF_BR + i * 256 + h] = acc;
    } else {
        // WeT[e][d] = We[d][e], bf16
        for (int it = 0; it < 16; ++it) {
            const int idx = it * 256 + tid;
            const int e = idx >> 6, d = idx & 63;
            wsu[U_WET + e * 64 + d] = f2bf(We[d * 64 + e]);
        }
    }
}

// =====================================================================
// Kernel 3 (fused): per-block 16 batch rows, 4 waves (one 64-col slab each).
// grid = 512 blocks; LDS 26.4 KB. Epilogue in registers + shfl;
// bias read as partial sums (8 ecc + 6 err slots).
// =====================================================================
__global__ __launch_bounds__(256, 4) void fused_main(
    const float* __restrict__ ecc, const float* __restrict__ err, const float* __restrict__ ehr,
    const float* __restrict__ wsf, const unsigned short* __restrict__ wsu,
    const float* __restrict__ Wa, const float* __restrict__ ba,
    const float* __restrict__ be_, const float* __restrict__ Wf2, const float* __restrict__ bf2,
    float* __restrict__ out)
{
    const unsigned short* awt_e = wsu + U_AET;
    const unsigned short* awt_r = wsu + U_ART;
    const unsigned short* wet   = wsu + U_WET;
    const float* biasE = wsf + OFF_BE;   // [8][256] partials
    const float* biasR = wsf + OFF_BR;   // [6][256] partials

    __shared__ __align__(16) char smem[ROWS * (SXE_LD + SXR_LD + SEH_LD) * 2];
    unsigned short* sxe = (unsigned short*)smem;          // [16][SXE_LD]
    unsigned short* sxr = sxe + ROWS * SXE_LD;            // [16][SXR_LD]
    unsigned short* seh = sxr + ROWS * SXR_LD;            // [16][SEH_LD]
    // epilogue scratch overlays sxe (used only after the post-MFMA barrier)
    float* pa_part = (float*)smem;                        // [4][16]
    float* at_arr  = pa_part + 64;                        // [16]
    float* po_part = at_arr + 16;                         // [4][16]

    const int tid = threadIdx.x;
    const int row0 = blockIdx.x * ROWS;

    // ---- stage X_ecc: 16 rows x 106 quads (real quads < 100) ----
    for (int it = 0; it < 7; ++it) {
        const int f = it * 256 + tid;
        if (f < ROWS * 106) {
            const int r = f / 106, q = f - r * 106;
            float4 v = make_float4(0.f, 0.f, 0.f, 0.f);
            if (q < 100) v = *(const float4*)(ecc + (size_t)(row0 + r) * KE + q * 4);
            const unsigned p0 = (unsigned)f2bf(v.x) | ((unsigned)f2bf(v.y) << 16);
            const unsigned p1 = (unsigned)f2bf(v.z) | ((unsigned)f2bf(v.w) << 16);
            *(uint2*)&sxe[r * SXE_LD + q * 4] = make_uint2(p0, p1);
        }
    }
    // ---- stage X_err: 16 rows x 82 quads (real quads < 75) ----
    for (int it = 0; it < 6; ++it) {
        const int f = it * 256 + tid;
        if (f < ROWS * 82) {
            const int r = f / 82, q = f - r * 82;
            float4 v = make_float4(0.f, 0.f, 0.f, 0.f);
            if (q < 75) v = *(const float4*)(err + (size_t)(row0 + r) * KR + q * 4);
            const unsigned p0 = (unsigned)f2bf(v.x) | ((unsigned)f2bf(v.y) << 16);
            const unsigned p1 = (unsigned)f2bf(v.z) | ((unsigned)f2bf(v.w) << 16);
            *(uint2*)&sxr[r * SXR_LD + q * 4] = make_uint2(p0, p1);
        }
    }
    // ---- stage ehr: 16 rows x 16 quads exactly (256 entries) ----
    {
        const int r = tid >> 4, q = tid & 15;
        const float4 v = *(const float4*)(ehr + (size_t)(row0 + r) * 64 + q * 4);
        const unsigned p0 = (unsigned)f2bf(v.x) | ((unsigned)f2bf(v.y) << 16);
        const unsigned p1 = (unsigned)f2bf(v.z) | ((unsigned)f2bf(v.w) << 16);
        *(uint2*)&seh[r * SEH_LD + q * 4] = make_uint2(p0, p1);
    }
    __syncthreads();

    const int wv = tid >> 6, lane = tid & 63;
    const int lm = lane & 15, lq = lane >> 4;
    const int n0 = wv * 64;

    floatx4 accE[4], accR[4], accH;
    accH = (floatx4){0.f, 0.f, 0.f, 0.f};
    #pragma unroll
    for (int nt = 0; nt < 4; ++nt) {
        accE[nt] = (floatx4){0.f, 0.f, 0.f, 0.f};
        accR[nt] = (floatx4){0.f, 0.f, 0.f, 0.f};
    }

    // ---- ehr_p = ehr @ We : wave handles e-slab wv (e = 16*wv + lm) ----
    #pragma unroll
    for (int kc = 0; kc < 2; ++kc) {
        const short8 b = *(const short8*)(wet + (wv * 16 + lm) * 64 + kc * 32 + lq * 8);
        const short8 a = *(const short8*)&seh[lm * SEH_LD + kc * 32 + lq * 8];
        accH = __builtin_amdgcn_mfma_f32_16x16x32_bf16(a, b, accH, 0, 0, 0);
    }
    // ---- ecc branch: 13 k-chunks ----
    #pragma unroll
    for (int kc = 0; kc < 13; ++kc) {
        const short8 a0 = *(const short8*)&sxe[lm * SXE_LD + kc * 32 + lq * 8];
        #pragma unroll
        for (int nt = 0; nt < 4; ++nt) {
            const short8 b = *(const short8*)(awt_e + (size_t)(n0 + nt * 16 + lm) * MEP + kc * 32 + lq * 8);
            accE[nt] = __builtin_amdgcn_mfma_f32_16x16x32_bf16(a0, b, accE[nt], 0, 0, 0);
        }
    }
    // ---- err branch: 10 k-chunks ----
    #pragma unroll
    for (int kc = 0; kc < 10; ++kc) {
        const short8 a0 = *(const short8*)&sxr[lm * SXR_LD + kc * 32 + lq * 8];
        #pragma unroll
        for (int nt = 0; nt < 4; ++nt) {
            const short8 b = *(const short8*)(awt_r + (size_t)(n0 + nt * 16 + lm) * MRP + kc * 32 + lq * 8);
            accR[nt] = __builtin_amdgcn_mfma_f32_16x16x32_bf16(a0, b, accR[nt], 0, 0, 0);
        }
    }

    // ---- per-lane epilogue constants (L2-hot; bias = sum of partials) ----
    float bE[4], bR[4], wa[4], wf[4];
    #pragma unroll
    for (int nt = 0; nt < 4; ++nt) {
        const int h = n0 + nt * 16 + lm;
        float se = 0.f;
        #pragma unroll
        for (int p = 0; p < 8; ++p) se += biasE[p * 256 + h];
        float sr = 0.f;
        #pragma unroll
        for (int p = 0; p < 6; ++p) sr += biasR[p * 256 + h];
        bE[nt] = se; bR[nt] = sr;
        wa[nt] = Wa[h]; wf[nt] = Wf2[h];
    }
    const int e_lane = wv * 16 + lm;
    const float eh_be = be_[e_lane];
    const float eh_wf = Wf2[256 + e_lane];

    // ---- pass 1: attention logits, pure register + shfl ----
    float pa_lane[4];
    #pragma unroll
    for (int rg = 0; rg < 4; ++rg) {
        float s = 0.f;
        #pragma unroll
        for (int nt = 0; nt < 4; ++nt) {
            const float ev = accE[nt][rg] + bE[nt];
            const float rv = accR[nt][rg] + bR[nt];
            s = fmaf(tanhf_(ev + rv), wa[nt], s);
        }
        s += __shfl_xor(s, 1, 64); s += __shfl_xor(s, 2, 64);
        s += __shfl_xor(s, 4, 64); s += __shfl_xor(s, 8, 64);
        pa_lane[rg] = s;
    }

    __syncthreads();   // all staging-LDS reads complete; safe to overlay scratch
    if (lm == 0) {
        #pragma unroll
        for (int rg = 0; rg < 4; ++rg)
            pa_part[wv * 16 + lq * 4 + rg] = pa_lane[rg];
    }
    __syncthreads();
    if (tid < 16)
        at_arr[tid] = sigmoidf_(pa_part[tid] + pa_part[16 + tid] + pa_part[32 + tid] + pa_part[48 + tid] + ba[0]);
    __syncthreads();

    // ---- pass 2: fused + EHR dot with Wf2, register + shfl ----
    float po_lane[4];
    #pragma unroll
    for (int rg = 0; rg < 4; ++rg) {
        const int r = lq * 4 + rg;
        const float at = at_arr[r];
        const float om = 1.f - at;
        float s = 0.f;
        #pragma unroll
        for (int nt = 0; nt < 4; ++nt) {
            const float ev = accE[nt][rg] + bE[nt];
            const float rv = accR[nt][rg] + bR[nt];
            s = fmaf(fmaxf(at * ev + om * rv, 0.f), wf[nt], s);
        }
        s = fmaf(fmaxf(accH[rg] + eh_be, 0.f), eh_wf, s);
        s += __shfl_xor(s, 1, 64); s += __shfl_xor(s, 2, 64);
        s += __shfl_xor(s, 4, 64); s += __shfl_xor(s, 8, 64);
        po_lane[rg] = s;
    }
    if (lm == 0) {
        #pragma unroll
        for (int rg = 0; rg < 4; ++rg)
            po_part[wv * 16 + lq * 4 + rg] = po_lane[rg];
    }
    __syncthreads();
    if (tid < 16)
        out[row0 + tid] = sigmoidf_(po_part[tid] + po_part[16 + tid] + po_part[32 + tid] + po_part[48 + tid] + bf2[0]);
}

// =====================================================================
extern "C" void kernel_launch(void* const* d_in, const int* in_sizes, int n_in,
                              void* d_out, int out_size, void* d_ws, size_t ws_size,
                              hipStream_t stream)
{
    (void)in_sizes; (void)n_in; (void)out_size; (void)ws_size;
    const float* ecc    = (const float*)d_in[0];
    const float* err    = (const float*)d_in[1];
    const float* ehr    = (const float*)d_in[2];
    const float* wt_ecc = (const float*)d_in[3];
    const float* bt_ecc = (const float*)d_in[4];
    const float* wt_err = (const float*)d_in[5];
    const float* bt_err = (const float*)d_in[6];
    const float* W0_ecc = (const float*)d_in[7];
    const float* W1_ecc = (const float*)d_in[8];
    const float* b_ecc  = (const float*)d_in[9];
    const float* W0_err = (const float*)d_in[10];
    const float* W1_err = (const float*)d_in[11];
    const float* b_err  = (const float*)d_in[12];
    const float* Wp_ecc = (const float*)d_in[13];
    const float* bp_ecc = (const float*)d_in[14];
    const float* Wp_err = (const float*)d_in[15];
    const float* bp_err = (const float*)d_in[16];
    const float* Wa     = (const float*)d_in[17];
    const float* ba     = (const float*)d_in[18];
    const float* We     = (const float*)d_in[19];
    const float* be     = (const float*)d_in[20];
    const float* Wf2    = (const float*)d_in[21];
    const float* bf2    = (const float*)d_in[22];
    float* wsf = (float*)d_ws;
    unsigned short* wsu = (unsigned short*)d_ws;
    float* out = (float*)d_out;

    fold_temporal<<<dim3(102), dim3(256), 0, stream>>>(
        wt_ecc, bt_ecc, wt_err, bt_err, W0_ecc, W1_ecc, b_ecc, W0_err, W1_err, b_err, wsf);
    fold_graph<<<dim3(44), dim3(256), 0, stream>>>(
        Wp_ecc, bp_ecc, Wp_err, bp_err, We, wsf, wsu);
    fused_main<<<dim3(B_TOT / ROWS), dim3(256), 0, stream>>>(
        ecc, err, ehr, wsf, wsu, Wa, ba, be, Wf2, bf2, out);
}

// Round 8
// 149.192 us; speedup vs baseline: 1.1401x; 1.0663x over previous
//
#include <hip/hip_runtime.h>
#include <math.h>

// ---------------- problem constants ----------------
#define B_TOT 8192
#define KE 400      // 16 nodes * 25 t (ecc K)
#define KR 300      // 12 nodes * 25 t (err K)
#define MEP 416     // ecc K padded to 13*32
#define MRP 320     // err K padded to 10*32

// LDS strides (bf16 elements), padded for bank-conflict avoidance
#define SXE_LD 424
#define SXR_LD 328
#define SEH_LD 72

// ---------------- workspace layout ----------------
// float offsets
#define OFF_WEFF0E 0
#define OFF_WEFF1E 1600
#define OFF_WEFF0R 3200
#define OFF_WEFF1R 4800
#define OFF_CVE    6400
#define OFF_CVR    6464
#define OFF_BE     6528
#define OFF_BR     6784
// ushort offsets (from d_ws base viewed as ushort*), 16B-aligned
#define U_AET 14080                   // AwT_ecc [256][416] bf16
#define U_ART (U_AET + 256 * MEP)     // AwT_err [256][320] bf16
#define U_WET (U_ART + 256 * MRP)     // WeT     [64][64]  bf16

typedef __attribute__((ext_vector_type(8))) short short8;
typedef __attribute__((ext_vector_type(4))) float floatx4;

__device__ __forceinline__ float sigmoidf_(float x) { return 1.f / (1.f + __expf(-x)); }
__device__ __forceinline__ float tanhf_(float x) { float e = __expf(2.f * x); return (e - 1.f) / (e + 1.f); }
__device__ __forceinline__ unsigned short f2bf(float x) {
    unsigned u = __float_as_uint(x);
    u += 0x7fffu + ((u >> 16) & 1u);          // round-to-nearest-even
    return (unsigned short)(u >> 16);
}

// =====================================================================
// Kernel 1: fold Conv1d into W0/W1 -> Weff [25][64] per (branch, order),
// cvec[64] = b + sum_ct bt[c]*(W0-W1)[ct]  (ring row-sum of L_hat = -1),
// and zero the bias accumulators (fold_graph atomicAdds into them).
// grid = 103 blocks x 256 threads
// =====================================================================
__global__ __launch_bounds__(256) void fold_temporal(
    const float* __restrict__ wt_ecc, const float* __restrict__ bt_ecc,
    const float* __restrict__ wt_err, const float* __restrict__ bt_err,
    const float* __restrict__ W0_ecc, const float* __restrict__ W1_ecc, const float* __restrict__ b_ecc,
    const float* __restrict__ W0_err, const float* __restrict__ W1_err, const float* __restrict__ b_err,
    float* __restrict__ ws)
{
    const int blk = blockIdx.x;
    const int tid = threadIdx.x;
    const int cq = tid >> 6;    // 0..3  (c-chunk of 8)
    const int g  = tid & 63;

    __shared__ float red[4][64];

    if (blk < 100) {
        const int m = blk / 25;       // 0: W0_ecc, 1: W1_ecc, 2: W0_err, 3: W1_err
        const int tin = blk % 25;
        const bool is_err = (m >= 2);
        const float* wt = is_err ? wt_err : wt_ecc;
        const float* W = (m & 1) ? (is_err ? W1_err : W1_ecc) : (is_err ? W0_err : W0_ecc);
        const int t0 = tin > 0 ? tin - 1 : 0;
        const int t1 = tin < 24 ? tin + 1 : 24;
        float s = 0.f;
        #pragma unroll
        for (int c8 = 0; c8 < 8; ++c8) {
            const int c = cq * 8 + c8;
            for (int t = t0; t <= t1; ++t) {
                const int k = tin - t + 1;           // 0..2
                s = fmaf(wt[c * 3 + k], W[(c * 25 + t) * 64 + g], s);
            }
        }
        red[cq][g] = s;
        __syncthreads();
        if (tid < 64)
            ws[m * 1600 + tin * 64 + g] = red[0][g] + red[1][g] + red[2][g] + red[3][g];
    } else if (blk < 102) {
        const bool is_err = (blk == 101);
        const float* bt = is_err ? bt_err : bt_ecc;
        const float* W0 = is_err ? W0_err : W0_ecc;
        const float* W1 = is_err ? W1_err : W1_ecc;
        const float* bb = is_err ? b_err : b_ecc;
        float s = 0.f;
        #pragma unroll
        for (int c8 = 0; c8 < 8; ++c8) {
            const int c = cq * 8 + c8;
            const float btc = bt[c];
            #pragma unroll
            for (int t = 0; t < 25; ++t) {
                const int ct = (c * 25 + t) * 64 + g;
                s = fmaf(btc, W0[ct] - W1[ct], s);
            }
        }
        red[cq][g] = s;
        __syncthreads();
        if (tid < 64)
            ws[(is_err ? OFF_CVR : OFF_CVE) + g] =
                bb[g] + red[0][g] + red[1][g] + red[2][g] + red[3][g];
    } else {
        // zero bias accumulators for fold_graph's atomicAdd
        ws[OFF_BE + tid] = 0.f;
        ws[OFF_BR + tid] = 0.f;
    }
}

// =====================================================================
// Kernel 2: fold Weff + ring stencil + Wp -> AwT (bf16, transposed, padded),
// biases (fp32, 16-way split + atomicAdd), WeT (bf16 transpose of We).
// 769 blocks: massively parallel (one k-row per block); the 151 MB of Wp
// re-reads are L2-resident (800 KB working set) and ride the 34.5 TB/s L2.
// Measured faster than the 44-block "amortized" variant (R7: +9 us).
// grid = 416 + 320 + 16 + 16 + 1 = 769 blocks x 256 threads
// =====================================================================
__global__ __launch_bounds__(256) void fold_graph(
    const float* __restrict__ Wp_ecc, const float* __restrict__ bp_ecc,
    const float* __restrict__ Wp_err, const float* __restrict__ bp_err,
    const float* __restrict__ We,
    float* __restrict__ wsf, unsigned short* __restrict__ wsu)
{
    const int blk = blockIdx.x;
    const int h = threadIdx.x;

    if (blk < MEP) {
        const int k = blk;
        float s = 0.f;
        if (k < KE) {
            const int v = k / 25, tin = k % 25;
            const int vp = (v + 1) & 15, vm = (v + 15) & 15;
            const float* w0 = wsf + OFF_WEFF0E + tin * 64;
            const float* w1 = wsf + OFF_WEFF1E + tin * 64;
            #pragma unroll 4
            for (int g = 0; g < 64; ++g) {
                s = fmaf(w0[g], Wp_ecc[(v * 64 + g) * 256 + h], s);
                s = fmaf(-0.5f * w1[g], Wp_ecc[(vp * 64 + g) * 256 + h] + Wp_ecc[(vm * 64 + g) * 256 + h], s);
            }
        }
        wsu[U_AET + (size_t)h * MEP + k] = f2bf(s);
    } else if (blk < MEP + MRP) {
        const int k = blk - MEP;
        float s = 0.f;
        if (k < KR) {
            const int v = k / 25, tin = k % 25;
            const int vp = (v + 1) % 12, vm = (v + 11) % 12;
            const float* w0 = wsf + OFF_WEFF0R + tin * 64;
            const float* w1 = wsf + OFF_WEFF1R + tin * 64;
            #pragma unroll 4
            for (int g = 0; g < 64; ++g) {
                s = fmaf(w0[g], Wp_err[(v * 64 + g) * 256 + h], s);
                s = fmaf(-0.5f * w1[g], Wp_err[(vp * 64 + g) * 256 + h] + Wp_err[(vm * 64 + g) * 256 + h], s);
            }
        }
        wsu[U_ART + (size_t)h * MRP + k] = f2bf(s);
    } else if (blk < MEP + MRP + 16) {
        // bias_ecc: 1024 (v,g) terms split into 16 chunks of 64
        const int i = blk - (MEP + MRP);
        const float* cv = wsf + OFF_CVE;
        float s = (i == 0) ? bp_ecc[h] : 0.f;
        #pragma unroll 4
        for (int jj = 0; jj < 64; ++jj) {
            const int j = i * 64 + jj;
            s = fmaf(cv[j & 63], Wp_ecc[(size_t)j * 256 + h], s);
        }
        atomicAdd(&wsf[OFF_BE + h], s);
    } else if (blk < MEP + MRP + 32) {
        // bias_err: 768 terms, 12 active chunks
        const int i = blk - (MEP + MRP + 16);
        const float* cv = wsf + OFF_CVR;
        float s = (i == 0) ? bp_err[h] : 0.f;
        if (i < 12) {
            #pragma unroll 4
            for (int jj = 0; jj < 64; ++jj) {
                const int j = i * 64 + jj;
                s = fmaf(cv[j & 63], Wp_err[(size_t)j * 256 + h], s);
            }
        }
        atomicAdd(&wsf[OFF_BR + h], s);
    } else {
        // WeT[e][d] = We[d][e], bf16
        for (int it = 0; it < 16; ++it) {
            const int idx = it * 256 + h;
            const int e = idx >> 6, d = idx & 63;
            wsu[U_WET + e * 64 + d] = f2bf(We[d * 64 + e]);
        }
    }
}

// =====================================================================
// Kernel 3 (fused): per-block 32 batch rows, 4 waves.
//   - stage X_ecc/X_err/ehr fp32->bf16 into LDS (51.5 KB -> 3 blocks/CU)
//   - MFMA 16x16x32 bf16: ecc_g, err_g (32x256), ehr_p (32x64)
//   - epilogue entirely in registers + shfl; only 288 floats of partials in LDS
// grid = 256 blocks x 256 threads   [measured best total: 149.8 us]
// =====================================================================
__global__ __launch_bounds__(256, 3) void fused_main(
    const float* __restrict__ ecc, const float* __restrict__ err, const float* __restrict__ ehr,
    const float* __restrict__ wsf, const unsigned short* __restrict__ wsu,
    const float* __restrict__ Wa, const float* __restrict__ ba,
    const float* __restrict__ be_, const float* __restrict__ Wf2, const float* __restrict__ bf2,
    float* __restrict__ out)
{
    const unsigned short* awt_e = wsu + U_AET;
    const unsigned short* awt_r = wsu + U_ART;
    const unsigned short* wet   = wsu + U_WET;
    const float* biasE = wsf + OFF_BE;
    const float* biasR = wsf + OFF_BR;

    __shared__ __align__(16) char smem[32 * SXE_LD * 2 + 32 * SXR_LD * 2 + 32 * SEH_LD * 2];
    unsigned short* sxe = (unsigned short*)smem;          // [32][SXE_LD]
    unsigned short* sxr = sxe + 32 * SXE_LD;              // [32][SXR_LD]
    unsigned short* seh = sxr + 32 * SXR_LD;              // [32][SEH_LD]
    // epilogue scratch overlays sxe (used only after the post-MFMA barrier)
    float* pa_part = (float*)smem;                        // [4][32]
    float* at_arr  = pa_part + 128;                       // [32]
    float* po_part = at_arr + 32;                         // [4][32]

    const int tid = threadIdx.x;
    const int row0 = blockIdx.x * 32;

    // ---- stage X_ecc: 32 rows x 106 quads (real quads < 100) ----
    for (int it = 0; it < 14; ++it) {
        const int f = it * 256 + tid;
        if (f < 32 * 106) {
            const int r = f / 106, q = f - r * 106;
            float4 v = make_float4(0.f, 0.f, 0.f, 0.f);
            if (q < 100) v = *(const float4*)(ecc + (size_t)(row0 + r) * KE + q * 4);
            const unsigned p0 = (unsigned)f2bf(v.x) | ((unsigned)f2bf(v.y) << 16);
            const unsigned p1 = (unsigned)f2bf(v.z) | ((unsigned)f2bf(v.w) << 16);
            *(uint2*)&sxe[r * SXE_LD + q * 4] = make_uint2(p0, p1);
        }
    }
    // ---- stage X_err: 32 rows x 82 quads (real quads < 75) ----
    for (int it = 0; it < 11; ++it) {
        const int f = it * 256 + tid;
        if (f < 32 * 82) {
            const int r = f / 82, q = f - r * 82;
            float4 v = make_float4(0.f, 0.f, 0.f, 0.f);
            if (q < 75) v = *(const float4*)(err + (size_t)(row0 + r) * KR + q * 4);
            const unsigned p0 = (unsigned)f2bf(v.x) | ((unsigned)f2bf(v.y) << 16);
            const unsigned p1 = (unsigned)f2bf(v.z) | ((unsigned)f2bf(v.w) << 16);
            *(uint2*)&sxr[r * SXR_LD + q * 4] = make_uint2(p0, p1);
        }
    }
    // ---- stage ehr: 32 rows x 16 quads exactly ----
    for (int it = 0; it < 2; ++it) {
        const int f = it * 256 + tid;
        const int r = f >> 4, q = f & 15;
        const float4 v = *(const float4*)(ehr + (size_t)(row0 + r) * 64 + q * 4);
        const unsigned p0 = (unsigned)f2bf(v.x) | ((unsigned)f2bf(v.y) << 16);
        const unsigned p1 = (unsigned)f2bf(v.z) | ((unsigned)f2bf(v.w) << 16);
        *(uint2*)&seh[r * SEH_LD + q * 4] = make_uint2(p0, p1);
    }
    __syncthreads();

    const int wv = tid >> 6, lane = tid & 63;
    const int lm = lane & 15, lq = lane >> 4;
    const int n0 = wv * 64;

    floatx4 accE[2][4], accR[2][4], accH[2];
    #pragma unroll
    for (int mt = 0; mt < 2; ++mt) {
        accH[mt] = (floatx4){0.f, 0.f, 0.f, 0.f};
        #pragma unroll
        for (int nt = 0; nt < 4; ++nt) {
            accE[mt][nt] = (floatx4){0.f, 0.f, 0.f, 0.f};
            accR[mt][nt] = (floatx4){0.f, 0.f, 0.f, 0.f};
        }
    }

    // ---- ehr_p = ehr @ We : wave handles e-slab wv (e = 16*wv + lm) ----
    #pragma unroll
    for (int kc = 0; kc < 2; ++kc) {
        const short8 b = *(const short8*)(wet + (wv * 16 + lm) * 64 + kc * 32 + lq * 8);
        #pragma unroll
        for (int mt = 0; mt < 2; ++mt) {
            const short8 a = *(const short8*)&seh[(mt * 16 + lm) * SEH_LD + kc * 32 + lq * 8];
            accH[mt] = __builtin_amdgcn_mfma_f32_16x16x32_bf16(a, b, accH[mt], 0, 0, 0);
        }
    }
    // ---- ecc branch: 13 k-chunks ----
    #pragma unroll
    for (int kc = 0; kc < 13; ++kc) {
        const short8 a0 = *(const short8*)&sxe[lm * SXE_LD + kc * 32 + lq * 8];
        const short8 a1 = *(const short8*)&sxe[(16 + lm) * SXE_LD + kc * 32 + lq * 8];
        #pragma unroll
        for (int nt = 0; nt < 4; ++nt) {
            const short8 b = *(const short8*)(awt_e + (size_t)(n0 + nt * 16 + lm) * MEP + kc * 32 + lq * 8);
            accE[0][nt] = __builtin_amdgcn_mfma_f32_16x16x32_bf16(a0, b, accE[0][nt], 0, 0, 0);
            accE[1][nt] = __builtin_amdgcn_mfma_f32_16x16x32_bf16(a1, b, accE[1][nt], 0, 0, 0);
        }
    }
    // ---- err branch: 10 k-chunks ----
    #pragma unroll
    for (int kc = 0; kc < 10; ++kc) {
        const short8 a0 = *(const short8*)&sxr[lm * SXR_LD + kc * 32 + lq * 8];
        const short8 a1 = *(const short8*)&sxr[(16 + lm) * SXR_LD + kc * 32 + lq * 8];
        #pragma unroll
        for (int nt = 0; nt < 4; ++nt) {
            const short8 b = *(const short8*)(awt_r + (size_t)(n0 + nt * 16 + lm) * MRP + kc * 32 + lq * 8);
            accR[0][nt] = __builtin_amdgcn_mfma_f32_16x16x32_bf16(a0, b, accR[0][nt], 0, 0, 0);
            accR[1][nt] = __builtin_amdgcn_mfma_f32_16x16x32_bf16(a1, b, accR[1][nt], 0, 0, 0);
        }
    }

    // ---- per-lane epilogue constants (L2-hot scalar loads) ----
    float bE[4], bR[4], wa[4], wf[4];
    #pragma unroll
    for (int nt = 0; nt < 4; ++nt) {
        const int h = n0 + nt * 16 + lm;
        bE[nt] = biasE[h]; bR[nt] = biasR[h]; wa[nt] = Wa[h]; wf[nt] = Wf2[h];
    }
    const int e_lane = wv * 16 + lm;
    const float eh_be = be_[e_lane];
    const float eh_wf = Wf2[256 + e_lane];

    // ---- pass 1: attention logits, pure register + shfl ----
    float pa_lane[2][4];
    #pragma unroll
    for (int mt = 0; mt < 2; ++mt)
        #pragma unroll
        for (int rg = 0; rg < 4; ++rg) {
            float s = 0.f;
            #pragma unroll
            for (int nt = 0; nt < 4; ++nt) {
                const float ev = accE[mt][nt][rg] + bE[nt];
                const float rv = accR[mt][nt][rg] + bR[nt];
                s = fmaf(tanhf_(ev + rv), wa[nt], s);
            }
            s += __shfl_xor(s, 1, 64); s += __shfl_xor(s, 2, 64);
            s += __shfl_xor(s, 4, 64); s += __shfl_xor(s, 8, 64);
            pa_lane[mt][rg] = s;
        }

    __syncthreads();   // all staging-LDS reads complete; safe to overlay scratch
    if (lm == 0) {
        #pragma unroll
        for (int mt = 0; mt < 2; ++mt)
            #pragma unroll
            for (int rg = 0; rg < 4; ++rg)
                pa_part[wv * 32 + mt * 16 + lq * 4 + rg] = pa_lane[mt][rg];
    }
    __syncthreads();
    if (tid < 32)
        at_arr[tid] = sigmoidf_(pa_part[tid] + pa_part[32 + tid] + pa_part[64 + tid] + pa_part[96 + tid] + ba[0]);
    __syncthreads();

    // ---- pass 2: fused + EHR dot with Wf2, register + shfl ----
    float po_lane[2][4];
    #pragma unroll
    for (int mt = 0; mt < 2; ++mt)
        #pragma unroll
        for (int rg = 0; rg < 4; ++rg) {
            const int r = mt * 16 + lq * 4 + rg;
            const float at = at_arr[r];
            const float om = 1.f - at;
            float s = 0.f;
            #pragma unroll
            for (int nt = 0; nt < 4; ++nt) {
                const float ev = accE[mt][nt][rg] + bE[nt];
                const float rv = accR[mt][nt][rg] + bR[nt];
                s = fmaf(fmaxf(at * ev + om * rv, 0.f), wf[nt], s);
            }
            s = fmaf(fmaxf(accH[mt][rg] + eh_be, 0.f), eh_wf, s);
            s += __shfl_xor(s, 1, 64); s += __shfl_xor(s, 2, 64);
            s += __shfl_xor(s, 4, 64); s += __shfl_xor(s, 8, 64);
            po_lane[mt][rg] = s;
        }
    if (lm == 0) {
        #pragma unroll
        for (int mt = 0; mt < 2; ++mt)
            #pragma unroll
            for (int rg = 0; rg < 4; ++rg)
                po_part[wv * 32 + mt * 16 + lq * 4 + rg] = po_lane[mt][rg];
    }
    __syncthreads();
    if (tid < 32)
        out[row0 + tid] = sigmoidf_(po_part[tid] + po_part[32 + tid] + po_part[64 + tid] + po_part[96 + tid] + bf2[0]);
}

// =====================================================================
extern "C" void kernel_launch(void* const* d_in, const int* in_sizes, int n_in,
                              void* d_out, int out_size, void* d_ws, size_t ws_size,
                              hipStream_t stream)
{
    (void)in_sizes; (void)n_in; (void)out_size; (void)ws_size;
    const float* ecc    = (const float*)d_in[0];
    const float* err    = (const float*)d_in[1];
    const float* ehr    = (const float*)d_in[2];
    const float* wt_ecc = (const float*)d_in[3];
    const float* bt_ecc = (const float*)d_in[4];
    const float* wt_err = (const float*)d_in[5];
    const float* bt_err = (const float*)d_in[6];
    const float* W0_ecc = (const float*)d_in[7];
    const float* W1_ecc = (const float*)d_in[8];
    const float* b_ecc  = (const float*)d_in[9];
    const float* W0_err = (const float*)d_in[10];
    const float* W1_err = (const float*)d_in[11];
    const float* b_err  = (const float*)d_in[12];
    const float* Wp_ecc = (const float*)d_in[13];
    const float* bp_ecc = (const float*)d_in[14];
    const float* Wp_err = (const float*)d_in[15];
    const float* bp_err = (const float*)d_in[16];
    const float* Wa     = (const float*)d_in[17];
    const float* ba     = (const float*)d_in[18];
    const float* We     = (const float*)d_in[19];
    const float* be     = (const float*)d_in[20];
    const float* Wf2    = (const float*)d_in[21];
    const float* bf2    = (const float*)d_in[22];
    float* wsf = (float*)d_ws;
    unsigned short* wsu = (unsigned short*)d_ws;
    float* out = (float*)d_out;

    fold_temporal<<<dim3(103), dim3(256), 0, stream>>>(
        wt_ecc, bt_ecc, wt_err, bt_err, W0_ecc, W1_ecc, b_ecc, W0_err, W1_err, b_err, wsf);
    fold_graph<<<dim3(MEP + MRP + 32 + 1), dim3(256), 0, stream>>>(
        Wp_ecc, bp_ecc, Wp_err, bp_err, We, wsf, wsu);
    fused_main<<<dim3(B_TOT / 32), dim3(256), 0, stream>>>(
        ecc, err, ehr, wsf, wsu, Wa, ba, be, Wf2, bf2, out);
}